// Round 9
// baseline (194.697 us; speedup 1.0000x reference)
//
#include <hip/hip_runtime.h>
#include <hip/hip_bf16.h>

#define BS 32768
#define NWP 10
#define DD 256
#define NEXP 6
#define HH 64
#define OUT_DIM 2
#define MB 32

typedef short bf16x8 __attribute__((ext_vector_type(8)));
typedef float f32x4 __attribute__((ext_vector_type(4)));

__device__ inline short bfs(float f) {
  __hip_bfloat16 h = __float2bfloat16(f);   // RNE
  return __builtin_bit_cast(short, h);
}

// ------- kernel 1: bucket by expert (block-aggregated atomics) -------
__global__ __launch_bounds__(1024) void bucket_k(const int* __restrict__ cmd,
                                                 int* __restrict__ counts,
                                                 unsigned short* __restrict__ lists) {
  __shared__ int wcnt[16][NEXP];
  __shared__ int wbase[16][NEXP];
  const int tid = threadIdx.x;
  const int w = tid >> 6, lane = tid & 63;
  const int b = blockIdx.x * 1024 + tid;          // grid covers exactly BS
  const int e = cmd[b];
  #pragma unroll
  for (int ee = 0; ee < NEXP; ++ee) {
    unsigned long long m = __ballot(e == ee);
    if (lane == 0) wcnt[w][ee] = __popcll(m);
  }
  __syncthreads();
  if (tid < NEXP) {
    int tot = 0, pf[16];
    #pragma unroll
    for (int ww = 0; ww < 16; ++ww) { pf[ww] = tot; tot += wcnt[ww][tid]; }
    const int bb = atomicAdd(&counts[tid], tot);  // 6 atomics per block
    #pragma unroll
    for (int ww = 0; ww < 16; ++ww) wbase[ww][tid] = bb + pf[ww];
  }
  __syncthreads();
  #pragma unroll
  for (int ee = 0; ee < NEXP; ++ee) {
    unsigned long long m = __ballot(e == ee);     // same mask as pass 1
    if (e == ee) {
      const int nbelow = __popcll(m & ((1ull << lane) - 1ull));
      lists[ee * BS + wbase[w][ee] + nbelow] = (unsigned short)b;
    }
  }
}

// ------- kernel 1b: prep, 54 blocks. parts 0-7: W1T slice; part 8: rw -------
__global__ void prep_k(const float* __restrict__ W1,
                       const float* __restrict__ re,
                       const float* __restrict__ b1,
                       short* __restrict__ W1T,
                       float* __restrict__ rw) {
  const int e = blockIdx.x;
  const int part = blockIdx.y;
  if (part < 8) {
    const int h = part * 8 + (threadIdx.x >> 5);
    const int d0 = (threadIdx.x & 31) * 8;
    const float* wp = W1 + (size_t)e * DD * HH + h;
    bf16x8 v;
    #pragma unroll
    for (int i = 0; i < 8; ++i) v[i] = bfs(wp[(size_t)(d0 + i) * HH]);
    *(bf16x8*)(W1T + ((size_t)e * HH + h) * DD + d0) = v;
  } else {
    for (int i = threadIdx.x; i < NWP * HH; i += 256) {
      const int n = i >> 6, h = i & 63;
      const float* rp = re + (size_t)n * DD;
      const float* wp = W1 + (size_t)e * DD * HH + h;
      float s = b1[e * HH + h];
      for (int d = 0; d < DD; ++d) s += rp[d] * wp[(size_t)d * HH];
      rw[((size_t)e * NWP + n) * HH + h] = s;     // fp32, exact
    }
  }
}

// ------- kernel 2: R8 skeleton; Wf 3/4 in regs + 1/4 in LDS; 3 waves/SIMD -------
__global__ __launch_bounds__(256, 3) void moe_gemm_k(
    const float* __restrict__ x,
    const short* __restrict__ W1T,     // [6][64][256] bf16, L2-resident
    const float* __restrict__ rwg,     // [6][10][64] f32 (b1 + re·W1)
    const float* __restrict__ W2,
    const float* __restrict__ b2,
    const int* __restrict__ counts,
    const unsigned short* __restrict__ lists,
    float* __restrict__ out)
{
  __shared__ short Xa[4][16 * DD];     // 32 KB per-wave single-buffer tiles
  __shared__ short Wb[16 * DD];        // 8 KB  W1T[e] rows h=48..63, swizzled
  __shared__ float rwl[NWP][68];       // 2.72 KB rw[e]
  __shared__ float w2l[HH * OUT_DIM];  // 0.5 KB  W2[e]
  __shared__ float po[MB * NWP][2];    // 2.56 KB pre-cumsum outputs
                                       // total 45.8 KB -> 3 blocks/CU

  const int e = blockIdx.y;
  const int cnt = counts[e];
  const int start = blockIdx.x * MB;
  if (start >= cnt) return;
  const int nb = min(MB, cnt - start);
  const int nrows = nb * NWP;

  const int tid = threadIdx.x;
  const int lane = tid & 63;
  const int wv = tid >> 6;
  const int arow = lane & 15;
  const int ag = lane >> 4;

  // A-fragments in regs for nt=0..2: Wf[nt][ks] = W1T[h=nt*16+arow][ks*32+ag*8..+8)
  bf16x8 Wf[3][8];                     // 96 VGPR, static indices only
  {
    const short* wb = W1T + ((size_t)e * HH + arow) * DD + ag * 8;
    #pragma unroll
    for (int nt = 0; nt < 3; ++nt)
      #pragma unroll
      for (int ks = 0; ks < 8; ++ks)
        Wf[nt][ks] = *(const bf16x8*)(wb + (size_t)(nt * 16) * DD + ks * 32);
  }
  // nt=3 quadrant -> LDS (coalesced 16B chunks; XOR key (hh&7)<<3 on short idx)
  {
    const short* src = W1T + ((size_t)e * HH + 48) * DD;
    for (int i = tid; i < 16 * DD / 8; i += 256) {       // 512 chunks
      const int hh = i >> 5;
      const int d = (i & 31) * 8;
      *(int4*)&Wb[hh * DD + (d ^ ((hh & 7) << 3))] = *(const int4*)(src + hh * DD + d);
    }
  }
  for (int i = tid; i < NWP * HH; i += 256)
    rwl[i >> 6][i & 63] = rwg[(size_t)e * NWP * HH + i];
  if (tid < HH * OUT_DIM) w2l[tid] = W2[(size_t)e * HH * OUT_DIM + tid];

  int bid_reg = (int)lists[e * BS + start + lane];

  __syncthreads();   // tables ready; no barriers until cumsum

  short* Xw = &Xa[wv][0];
  const int ntile = (nrows + 15) >> 4;

  for (int t = wv; t < ntile; t += 4) {          // tiles disjoint per wave
    // stage 16 rows: coalesced 1KB/instr loads; LLVM pipelines freely
    #pragma unroll
    for (int r = 0; r < 16; ++r) {
      const int rowc = min(t * 16 + r, nrows - 1);
      const int item = rowc / NWP;
      const int nn = rowc - item * NWP;
      const int gb = __shfl(bid_reg, item);      // uniform idx, all lanes active
      const float4 xv = *(const float4*)(x + ((size_t)gb * NWP + nn) * DD + lane * 4);
      short4 pk = make_short4(bfs(xv.x), bfs(xv.y), bfs(xv.z), bfs(xv.w));
      *(short4*)&Xw[r * DD + ((lane * 4) ^ ((r & 7) << 3))] = pk;
    }

    // compute: S^T = W1^T · x ; 8 ds_reads (x) + 8 ds_reads (Wb) per tile
    f32x4 acc[4] = {{0,0,0,0},{0,0,0,0},{0,0,0,0},{0,0,0,0}};
    #pragma unroll
    for (int ks = 0; ks < 8; ++ks) {
      const int kidx = ks * 32 + ag * 8;
      const int kswz = kidx ^ ((arow & 7) << 3);
      const bf16x8 bx = *(const bf16x8*)&Xw[arow * DD + kswz];
      acc[0] = __builtin_amdgcn_mfma_f32_16x16x32_bf16(Wf[0][ks], bx, acc[0], 0, 0, 0);
      acc[1] = __builtin_amdgcn_mfma_f32_16x16x32_bf16(Wf[1][ks], bx, acc[1], 0, 0, 0);
      acc[2] = __builtin_amdgcn_mfma_f32_16x16x32_bf16(Wf[2][ks], bx, acc[2], 0, 0, 0);
      const bf16x8 aw3 = *(const bf16x8*)&Wb[arow * DD + kswz];
      acc[3] = __builtin_amdgcn_mfma_f32_16x16x32_bf16(aw3, bx, acc[3], 0, 0, 0);
    }

    // thin epilogue: lane owns batch-row t*16+arow; h = nt*16+ag*4+rg
    const int row = t * 16 + arow;
    const int rowc = min(row, nrows - 1);
    const int nn = rowc - (rowc / NWP) * NWP;
    float p0 = 0.f, p1 = 0.f;
    #pragma unroll
    for (int nt = 0; nt < 4; ++nt) {
      const int h0 = nt * 16 + ag * 4;
      const float4 rv = *(const float4*)&rwl[nn][h0];
      const float4 wa = *(const float4*)&w2l[h0 * 2];       // h0:{o0,o1} h1:{o0,o1}
      const float4 wb = *(const float4*)&w2l[h0 * 2 + 4];   // h2,h3
      const float h0v = fmaxf(acc[nt][0] + rv.x, 0.f);
      const float h1v = fmaxf(acc[nt][1] + rv.y, 0.f);
      const float h2v = fmaxf(acc[nt][2] + rv.z, 0.f);
      const float h3v = fmaxf(acc[nt][3] + rv.w, 0.f);
      p0 += h0v * wa.x + h1v * wa.z + h2v * wb.x + h3v * wb.z;
      p1 += h0v * wa.y + h1v * wa.w + h2v * wb.y + h3v * wb.w;
    }
    p0 += __shfl_xor(p0, 16); p1 += __shfl_xor(p1, 16);     // reduce over ag
    p0 += __shfl_xor(p0, 32); p1 += __shfl_xor(p1, 32);
    if (ag == 0 && row < nrows) {     // unique writer: tiles disjoint per wave
      po[row][0] = p0;
      po[row][1] = p1;
    }
  }

  __syncthreads();   // all po stores visible

  // fused cumsum + writeout: one thread per batch item
  if (tid < nb) {
    const int gb = (int)lists[e * BS + start + tid];
    const float bb0 = b2[e * OUT_DIM + 0];
    const float bb1 = b2[e * OUT_DIM + 1];
    float v[NWP * OUT_DIM];
    float s0 = 0.f, s1 = 0.f;
    #pragma unroll
    for (int n = 0; n < NWP; ++n) {
      s0 += po[tid * NWP + n][0] + bb0;
      s1 += po[tid * NWP + n][1] + bb1;
      v[n * 2 + 0] = s0;
      v[n * 2 + 1] = s1;
    }
    float4* op = (float4*)(out + (size_t)gb * NWP * OUT_DIM);
    #pragma unroll
    for (int q = 0; q < 5; ++q)
      op[q] = make_float4(v[q * 4], v[q * 4 + 1], v[q * 4 + 2], v[q * 4 + 3]);
  }
}

extern "C" void kernel_launch(void* const* d_in, const int* in_sizes, int n_in,
                              void* d_out, int out_size, void* d_ws, size_t ws_size,
                              hipStream_t stream) {
  const float* x          = (const float*)d_in[0];
  const int*   meas       = (const int*)d_in[1];
  const float* rank_embed = (const float*)d_in[2];
  const float* W1         = (const float*)d_in[3];
  const float* b1         = (const float*)d_in[4];
  const float* W2         = (const float*)d_in[5];
  const float* b2         = (const float*)d_in[6];
  float* out = (float*)d_out;

  int* counts = (int*)d_ws;                                      // @0
  unsigned short* lists = (unsigned short*)((char*)d_ws + 4096); // 384 KB
  short* W1T = (short*)((char*)d_ws + (448 << 10));              // 192 KB bf16
  float* rw  = (float*)((char*)d_ws + (704 << 10));              // 15.4 KB f32

  hipMemsetAsync(d_ws, 0, 256, stream);
  bucket_k<<<BS / 1024, 1024, 0, stream>>>(meas, counts, lists);
  prep_k<<<dim3(NEXP, 9), 256, 0, stream>>>(W1, rank_embed, b1, W1T, rw);
  dim3 gg((BS + MB - 1) / MB, NEXP);
  moe_gemm_k<<<gg, 256, 0, stream>>>(x, W1T, rw, W2, b2, counts, lists, out);
}

// Round 10
// 193.658 us; speedup vs baseline: 1.0054x; 1.0054x over previous
//
#include <hip/hip_runtime.h>
#include <hip/hip_bf16.h>

#define BS 32768
#define NWP 10
#define DD 256
#define NEXP 6
#define HH 64
#define OUT_DIM 2
#define MB 32

typedef short bf16x8 __attribute__((ext_vector_type(8)));
typedef float f32x4 __attribute__((ext_vector_type(4)));

__device__ inline short bfs(float f) {
  __hip_bfloat16 h = __float2bfloat16(f);   // RNE
  return __builtin_bit_cast(short, h);
}

// ------- kernel 1: bucket by expert (block-aggregated atomics) -------
__global__ __launch_bounds__(1024) void bucket_k(const int* __restrict__ cmd,
                                                 int* __restrict__ counts,
                                                 unsigned short* __restrict__ lists) {
  __shared__ int wcnt[16][NEXP];
  __shared__ int wbase[16][NEXP];
  const int tid = threadIdx.x;
  const int w = tid >> 6, lane = tid & 63;
  const int b = blockIdx.x * 1024 + tid;          // grid covers exactly BS
  const int e = cmd[b];
  #pragma unroll
  for (int ee = 0; ee < NEXP; ++ee) {
    unsigned long long m = __ballot(e == ee);
    if (lane == 0) wcnt[w][ee] = __popcll(m);
  }
  __syncthreads();
  if (tid < NEXP) {
    int tot = 0, pf[16];
    #pragma unroll
    for (int ww = 0; ww < 16; ++ww) { pf[ww] = tot; tot += wcnt[ww][tid]; }
    const int bb = atomicAdd(&counts[tid], tot);  // 6 atomics per block
    #pragma unroll
    for (int ww = 0; ww < 16; ++ww) wbase[ww][tid] = bb + pf[ww];
  }
  __syncthreads();
  #pragma unroll
  for (int ee = 0; ee < NEXP; ++ee) {
    unsigned long long m = __ballot(e == ee);     // same mask as pass 1
    if (e == ee) {
      const int nbelow = __popcll(m & ((1ull << lane) - 1ull));
      lists[ee * BS + wbase[w][ee] + nbelow] = (unsigned short)b;
    }
  }
}

// ------- kernel 1b: prep, 54 blocks. parts 0-7: W1T slice; part 8: rw -------
__global__ void prep_k(const float* __restrict__ W1,
                       const float* __restrict__ re,
                       const float* __restrict__ b1,
                       short* __restrict__ W1T,
                       float* __restrict__ rw) {
  const int e = blockIdx.x;
  const int part = blockIdx.y;
  if (part < 8) {
    const int h = part * 8 + (threadIdx.x >> 5);
    const int d0 = (threadIdx.x & 31) * 8;
    const float* wp = W1 + (size_t)e * DD * HH + h;
    bf16x8 v;
    #pragma unroll
    for (int i = 0; i < 8; ++i) v[i] = bfs(wp[(size_t)(d0 + i) * HH]);
    *(bf16x8*)(W1T + ((size_t)e * HH + h) * DD + d0) = v;
  } else {
    for (int i = threadIdx.x; i < NWP * HH; i += 256) {
      const int n = i >> 6, h = i & 63;
      const float* rp = re + (size_t)n * DD;
      const float* wp = W1 + (size_t)e * DD * HH + h;
      float s = b1[e * HH + h];
      for (int d = 0; d < DD; ++d) s += rp[d] * wp[(size_t)d * HH];
      rw[((size_t)e * NWP + n) * HH + h] = s;     // fp32, exact
    }
  }
}

// ------- kernel 1c: build work queue [(e<<16)|start] -------
__global__ void build_q_k(const int* __restrict__ counts, int* __restrict__ qmeta) {
  __shared__ int base[NEXP + 1];
  if (threadIdx.x == 0) {
    int tot = 0;
    #pragma unroll
    for (int e = 0; e < NEXP; ++e) {
      base[e] = tot;
      tot += (counts[e] + MB - 1) / MB;
    }
    base[NEXP] = tot;
    qmeta[17] = tot;                 // qtot (qhead at [16] zeroed by memset)
  }
  __syncthreads();
  #pragma unroll
  for (int e = 0; e < NEXP; ++e) {
    const int ne = base[e + 1] - base[e];
    for (int j = threadIdx.x; j < ne; j += blockDim.x)
      qmeta[32 + base[e] + j] = (e << 16) | (j * MB);
  }
}

// ------- kernel 2: persistent blocks + work queue; R8 chunk body -------
__global__ __launch_bounds__(256, 2) void moe_gemm_k(
    const float* __restrict__ x,
    const short* __restrict__ W1T,     // [6][64][256] bf16, L2-resident
    const float* __restrict__ rwg,     // [6][10][64] f32 (b1 + re·W1)
    const float* __restrict__ W2,
    const float* __restrict__ b2,
    int* __restrict__ qmeta,           // [0..5] counts, [16] qhead, [17] qtot, [32..] work
    const unsigned short* __restrict__ lists,
    float* __restrict__ out)
{
  __shared__ short Xa[4][16 * DD];     // 32 KB per-wave single-buffer tiles
  __shared__ float rwl[NWP][68];       // 2.72 KB rw[e]
  __shared__ float w2l[HH * OUT_DIM];  // 0.5 KB  W2[e]
  __shared__ float po[MB * NWP][2];    // 2.56 KB pre-cumsum outputs
  __shared__ int s_wi;                 // total ~37.8 KB

  const int tid = threadIdx.x;
  const int lane = tid & 63;
  const int wv = tid >> 6;
  const int arow = lane & 15;
  const int ag = lane >> 4;
  const int qtot = qmeta[17];

  for (;;) {
    if (tid == 0) s_wi = atomicAdd(&qmeta[16], 1);
    __syncthreads();                   // s_wi visible; prev chunk's po fully consumed
    const int wi = s_wi;
    if (wi >= qtot) break;             // uniform exit
    const int ent = qmeta[32 + wi];
    const int e = ent >> 16;
    const int start = ent & 0xffff;
    const int cnt = qmeta[e];
    const int nb = min(MB, cnt - start);
    const int nrows = nb * NWP;

    // hoist all A-fragments: Wf[nt][ks] = W1T[h=nt*16+arow][ks*32+ag*8 .. +8)
    bf16x8 Wf[4][8];                   // 128 VGPR, static indices only
    {
      const short* wb = W1T + ((size_t)e * HH + arow) * DD + ag * 8;
      #pragma unroll
      for (int nt = 0; nt < 4; ++nt)
        #pragma unroll
        for (int ks = 0; ks < 8; ++ks)
          Wf[nt][ks] = *(const bf16x8*)(wb + (size_t)(nt * 16) * DD + ks * 32);
    }
    for (int i = tid; i < NWP * HH; i += 256)
      rwl[i >> 6][i & 63] = rwg[(size_t)e * NWP * HH + i];
    if (tid < HH * OUT_DIM) w2l[tid] = W2[(size_t)e * HH * OUT_DIM + tid];

    int bid_reg = (int)lists[e * BS + start + lane];

    __syncthreads();                   // tables ready

    short* Xw = &Xa[wv][0];
    const int ntile = (nrows + 15) >> 4;

    for (int t = wv; t < ntile; t += 4) {        // tiles disjoint per wave
      // stage 16 rows: coalesced 1KB/instr loads; LLVM pipelines freely
      #pragma unroll
      for (int r = 0; r < 16; ++r) {
        const int rowc = min(t * 16 + r, nrows - 1);
        const int item = rowc / NWP;
        const int nn = rowc - item * NWP;
        const int gb = __shfl(bid_reg, item);    // uniform idx, all lanes active
        const float4 xv = *(const float4*)(x + ((size_t)gb * NWP + nn) * DD + lane * 4);
        short4 pk = make_short4(bfs(xv.x), bfs(xv.y), bfs(xv.z), bfs(xv.w));
        *(short4*)&Xw[r * DD + ((lane * 4) ^ ((r & 7) << 3))] = pk;
      }

      // compute: S^T = W1^T · x ; only 8 ds_reads per tile
      f32x4 acc[4] = {{0,0,0,0},{0,0,0,0},{0,0,0,0},{0,0,0,0}};
      #pragma unroll
      for (int ks = 0; ks < 8; ++ks) {
        const int kidx = ks * 32 + ag * 8;
        const bf16x8 bx = *(const bf16x8*)&Xw[arow * DD + (kidx ^ ((arow & 7) << 3))];
        #pragma unroll
        for (int nt = 0; nt < 4; ++nt)
          acc[nt] = __builtin_amdgcn_mfma_f32_16x16x32_bf16(Wf[nt][ks], bx, acc[nt], 0, 0, 0);
      }

      // thin epilogue: lane owns batch-row t*16+arow; h = nt*16+ag*4+rg
      const int row = t * 16 + arow;
      const int rowc = min(row, nrows - 1);
      const int nn = rowc - (rowc / NWP) * NWP;
      float p0 = 0.f, p1 = 0.f;
      #pragma unroll
      for (int nt = 0; nt < 4; ++nt) {
        const int h0 = nt * 16 + ag * 4;
        const float4 rv = *(const float4*)&rwl[nn][h0];
        const float4 wa = *(const float4*)&w2l[h0 * 2];       // h0:{o0,o1} h1:{o0,o1}
        const float4 wb = *(const float4*)&w2l[h0 * 2 + 4];   // h2,h3
        const float h0v = fmaxf(acc[nt][0] + rv.x, 0.f);
        const float h1v = fmaxf(acc[nt][1] + rv.y, 0.f);
        const float h2v = fmaxf(acc[nt][2] + rv.z, 0.f);
        const float h3v = fmaxf(acc[nt][3] + rv.w, 0.f);
        p0 += h0v * wa.x + h1v * wa.z + h2v * wb.x + h3v * wb.z;
        p1 += h0v * wa.y + h1v * wa.w + h2v * wb.y + h3v * wb.w;
      }
      p0 += __shfl_xor(p0, 16); p1 += __shfl_xor(p1, 16);     // reduce over ag
      p0 += __shfl_xor(p0, 32); p1 += __shfl_xor(p1, 32);
      if (ag == 0 && row < nrows) {   // unique writer: tiles disjoint per wave
        po[row][0] = p0;
        po[row][1] = p1;
      }
    }

    __syncthreads();                   // all po stores visible

    // fused cumsum + writeout: one thread per batch item
    if (tid < nb) {
      const int gb = (int)lists[e * BS + start + tid];
      const float bb0 = b2[e * OUT_DIM + 0];
      const float bb1 = b2[e * OUT_DIM + 1];
      float v[NWP * OUT_DIM];
      float s0 = 0.f, s1 = 0.f;
      #pragma unroll
      for (int n = 0; n < NWP; ++n) {
        s0 += po[tid * NWP + n][0] + bb0;
        s1 += po[tid * NWP + n][1] + bb1;
        v[n * 2 + 0] = s0;
        v[n * 2 + 1] = s1;
      }
      float4* op = (float4*)(out + (size_t)gb * NWP * OUT_DIM);
      #pragma unroll
      for (int q = 0; q < 5; ++q)
        op[q] = make_float4(v[q * 4], v[q * 4 + 1], v[q * 4 + 2], v[q * 4 + 3]);
    }
  }
}

extern "C" void kernel_launch(void* const* d_in, const int* in_sizes, int n_in,
                              void* d_out, int out_size, void* d_ws, size_t ws_size,
                              hipStream_t stream) {
  const float* x          = (const float*)d_in[0];
  const int*   meas       = (const int*)d_in[1];
  const float* rank_embed = (const float*)d_in[2];
  const float* W1         = (const float*)d_in[3];
  const float* b1         = (const float*)d_in[4];
  const float* W2         = (const float*)d_in[5];
  const float* b2         = (const float*)d_in[6];
  float* out = (float*)d_out;

  int* qmeta = (int*)d_ws;                                       // counts/qhead/qtot/work
  unsigned short* lists = (unsigned short*)((char*)d_ws + 8192); // 384 KB
  short* W1T = (short*)((char*)d_ws + (452 << 10));              // 192 KB bf16
  float* rw  = (float*)((char*)d_ws + (708 << 10));              // 15.4 KB f32

  hipMemsetAsync(d_ws, 0, 8192, stream);   // counts + qhead + qtot + work region
  bucket_k<<<BS / 1024, 1024, 0, stream>>>(meas, qmeta, lists);
  prep_k<<<dim3(NEXP, 9), 256, 0, stream>>>(W1, rank_embed, b1, W1T, rw);
  build_q_k<<<1, 256, 0, stream>>>(qmeta, qmeta);
  moe_gemm_k<<<512, 256, 0, stream>>>(x, W1T, rw, W2, b2, qmeta, lists, out);
}

// Round 11
// 111.622 us; speedup vs baseline: 1.7443x; 1.7350x over previous
//
#include <hip/hip_runtime.h>
#include <hip/hip_bf16.h>

#define BS 32768
#define NWP 10
#define DD 256
#define NEXP 6
#define HH 64
#define OUT_DIM 2
#define MB 32
#define MAXQ 1032   // >= sum_e ceil(cnt_e/MB) worst case (1029)

typedef short bf16x8 __attribute__((ext_vector_type(8)));
typedef float f32x4 __attribute__((ext_vector_type(4)));

__device__ inline short bfs(float f) {
  __hip_bfloat16 h = __float2bfloat16(f);   // RNE
  return __builtin_bit_cast(short, h);
}

// ------- kernel 1: bucket by expert (block-aggregated atomics, int lists) -------
__global__ __launch_bounds__(1024) void bucket_k(const int* __restrict__ cmd,
                                                 int* __restrict__ counts,
                                                 int* __restrict__ lists) {
  __shared__ int wcnt[16][NEXP];
  __shared__ int wbase[16][NEXP];
  const int tid = threadIdx.x;
  const int w = tid >> 6, lane = tid & 63;
  const int b = blockIdx.x * 1024 + tid;          // grid covers exactly BS
  const int e = cmd[b];
  #pragma unroll
  for (int ee = 0; ee < NEXP; ++ee) {
    unsigned long long m = __ballot(e == ee);
    if (lane == 0) wcnt[w][ee] = __popcll(m);
  }
  __syncthreads();
  if (tid < NEXP) {
    int tot = 0, pf[16];
    #pragma unroll
    for (int ww = 0; ww < 16; ++ww) { pf[ww] = tot; tot += wcnt[ww][tid]; }
    const int bb = atomicAdd(&counts[tid], tot);  // 6 atomics per block
    #pragma unroll
    for (int ww = 0; ww < 16; ++ww) wbase[ww][tid] = bb + pf[ww];
  }
  __syncthreads();
  #pragma unroll
  for (int ee = 0; ee < NEXP; ++ee) {
    unsigned long long m = __ballot(e == ee);     // same mask as pass 1
    if (e == ee) {
      const int nbelow = __popcll(m & ((1ull << lane) - 1ull));
      lists[ee * BS + wbase[w][ee] + nbelow] = b;
    }
  }
}

// ------- kernel 1b: prep, 54 blocks. parts 0-7: W1T slice; part 8: rw -------
__global__ void prep_k(const float* __restrict__ W1,
                       const float* __restrict__ re,
                       const float* __restrict__ b1,
                       short* __restrict__ W1T,
                       float* __restrict__ rw) {
  const int e = blockIdx.x;
  const int part = blockIdx.y;
  if (part < 8) {
    const int h = part * 8 + (threadIdx.x >> 5);
    const int d0 = (threadIdx.x & 31) * 8;
    const float* wp = W1 + (size_t)e * DD * HH + h;
    bf16x8 v;
    #pragma unroll
    for (int i = 0; i < 8; ++i) v[i] = bfs(wp[(size_t)(d0 + i) * HH]);
    *(bf16x8*)(W1T + ((size_t)e * HH + h) * DD + d0) = v;
  } else {
    for (int i = threadIdx.x; i < NWP * HH; i += 256) {
      const int n = i >> 6, h = i & 63;
      const float* rp = re + (size_t)n * DD;
      const float* wp = W1 + (size_t)e * DD * HH + h;
      float s = b1[e * HH + h];
      for (int d = 0; d < DD; ++d) s += rp[d] * wp[(size_t)d * HH];
      rw[((size_t)e * NWP + n) * HH + h] = s;     // fp32, exact
    }
  }
}

// ------- kernel 1c: build packed work queue [(e<<16)|start] -------
__global__ void build_q_k(const int* __restrict__ counts, int* __restrict__ qmeta) {
  __shared__ int base[NEXP + 1];
  if (threadIdx.x == 0) {
    int tot = 0;
    #pragma unroll
    for (int e = 0; e < NEXP; ++e) {
      base[e] = tot;
      tot += (counts[e] + MB - 1) / MB;
    }
    base[NEXP] = tot;
    qmeta[17] = tot;                 // qtot
  }
  __syncthreads();
  #pragma unroll
  for (int e = 0; e < NEXP; ++e) {
    const int ne = base[e + 1] - base[e];
    for (int j = threadIdx.x; j < ne; j += blockDim.x)
      qmeta[32 + base[e] + j] = (e << 16) | (j * MB);
  }
}

// ------- kernel 2: R8 body; packed 1D grid; scalar gb loads -------
__global__ __launch_bounds__(256, 2) void moe_gemm_k(
    const float* __restrict__ x,
    const short* __restrict__ W1T,     // [6][64][256] bf16, L2-resident
    const float* __restrict__ rwg,     // [6][10][64] f32 (b1 + re·W1)
    const float* __restrict__ W2,
    const float* __restrict__ b2,
    const int* __restrict__ qmeta,     // [0..5] counts, [17] qtot, [32..] work
    const int* __restrict__ lists,
    float* __restrict__ out)
{
  __shared__ short Xa[4][16 * DD];     // 32 KB per-wave single-buffer tiles
  __shared__ float rwl[NWP][68];       // 2.72 KB rw[e]
  __shared__ float w2l[HH * OUT_DIM];  // 0.5 KB  W2[e]
  __shared__ float po[MB * NWP][2];    // 2.56 KB pre-cumsum outputs

  const int wi = blockIdx.x;
  if (wi >= qmeta[17]) return;         // <=6 idle blocks total
  const int ent = qmeta[32 + wi];
  const int e = ent >> 16;
  const int start = ent & 0xffff;
  const int cnt = qmeta[e];
  const int nb = min(MB, cnt - start);
  const int nrows = nb * NWP;

  const int tid = threadIdx.x;
  const int lane = tid & 63;
  const int wv = tid >> 6;
  const int arow = lane & 15;
  const int ag = lane >> 4;

  // hoist all A-fragments: Wf[nt][ks] = W1T[h=nt*16+arow][ks*32+ag*8 .. +8)
  bf16x8 Wf[4][8];                     // 128 VGPR, static indices only
  {
    const short* wb = W1T + ((size_t)e * HH + arow) * DD + ag * 8;
    #pragma unroll
    for (int nt = 0; nt < 4; ++nt)
      #pragma unroll
      for (int ks = 0; ks < 8; ++ks)
        Wf[nt][ks] = *(const bf16x8*)(wb + (size_t)(nt * 16) * DD + ks * 32);
  }
  for (int i = tid; i < NWP * HH; i += 256)
    rwl[i >> 6][i & 63] = rwg[(size_t)e * NWP * HH + i];
  if (tid < HH * OUT_DIM) w2l[tid] = W2[(size_t)e * HH * OUT_DIM + tid];

  __syncthreads();   // tables ready; no barriers until cumsum

  short* Xw = &Xa[wv][0];
  const int ntile = (nrows + 15) >> 4;
  const int lbase = e * BS + start;

  for (int t = wv; t < ntile; t += 4) {          // tiles disjoint per wave
    // stage 16 rows: row index is wave-uniform -> scalar gb via s_load path
    #pragma unroll
    for (int r = 0; r < 16; ++r) {
      const int rowu = __builtin_amdgcn_readfirstlane(min(t * 16 + r, nrows - 1));
      const int item = rowu / NWP;
      const int nn = rowu - item * NWP;
      const int gb = lists[lbase + item];        // uniform address -> scalar load
      const float4 xv = *(const float4*)(x + ((size_t)gb * NWP + nn) * DD + lane * 4);
      short4 pk = make_short4(bfs(xv.x), bfs(xv.y), bfs(xv.z), bfs(xv.w));
      *(short4*)&Xw[r * DD + ((lane * 4) ^ ((r & 7) << 3))] = pk;
    }

    // compute: S^T = W1^T · x ; only 8 ds_reads per tile
    f32x4 acc[4] = {{0,0,0,0},{0,0,0,0},{0,0,0,0},{0,0,0,0}};
    #pragma unroll
    for (int ks = 0; ks < 8; ++ks) {
      const int kidx = ks * 32 + ag * 8;
      const bf16x8 bx = *(const bf16x8*)&Xw[arow * DD + (kidx ^ ((arow & 7) << 3))];
      #pragma unroll
      for (int nt = 0; nt < 4; ++nt)
        acc[nt] = __builtin_amdgcn_mfma_f32_16x16x32_bf16(Wf[nt][ks], bx, acc[nt], 0, 0, 0);
    }

    // thin epilogue: lane owns batch-row t*16+arow; h = nt*16+ag*4+rg
    const int row = t * 16 + arow;
    const int rowc = min(row, nrows - 1);
    const int nn = rowc - (rowc / NWP) * NWP;
    float p0 = 0.f, p1 = 0.f;
    #pragma unroll
    for (int nt = 0; nt < 4; ++nt) {
      const int h0 = nt * 16 + ag * 4;
      const float4 rv = *(const float4*)&rwl[nn][h0];
      const float4 wa = *(const float4*)&w2l[h0 * 2];       // h0:{o0,o1} h1:{o0,o1}
      const float4 wb = *(const float4*)&w2l[h0 * 2 + 4];   // h2,h3
      const float h0v = fmaxf(acc[nt][0] + rv.x, 0.f);
      const float h1v = fmaxf(acc[nt][1] + rv.y, 0.f);
      const float h2v = fmaxf(acc[nt][2] + rv.z, 0.f);
      const float h3v = fmaxf(acc[nt][3] + rv.w, 0.f);
      p0 += h0v * wa.x + h1v * wa.z + h2v * wb.x + h3v * wb.z;
      p1 += h0v * wa.y + h1v * wa.w + h2v * wb.y + h3v * wb.w;
    }
    p0 += __shfl_xor(p0, 16); p1 += __shfl_xor(p1, 16);     // reduce over ag
    p0 += __shfl_xor(p0, 32); p1 += __shfl_xor(p1, 32);
    if (ag == 0 && row < nrows) {     // unique writer: tiles disjoint per wave
      po[row][0] = p0;
      po[row][1] = p1;
    }
  }

  __syncthreads();   // all po stores visible

  // fused cumsum + writeout: one thread per batch item
  if (tid < nb) {
    const int gb = lists[lbase + tid];
    const float bb0 = b2[e * OUT_DIM + 0];
    const float bb1 = b2[e * OUT_DIM + 1];
    float v[NWP * OUT_DIM];
    float s0 = 0.f, s1 = 0.f;
    #pragma unroll
    for (int n = 0; n < NWP; ++n) {
      s0 += po[tid * NWP + n][0] + bb0;
      s1 += po[tid * NWP + n][1] + bb1;
      v[n * 2 + 0] = s0;
      v[n * 2 + 1] = s1;
    }
    float4* op = (float4*)(out + (size_t)gb * NWP * OUT_DIM);
    #pragma unroll
    for (int q = 0; q < 5; ++q)
      op[q] = make_float4(v[q * 4], v[q * 4 + 1], v[q * 4 + 2], v[q * 4 + 3]);
  }
}

extern "C" void kernel_launch(void* const* d_in, const int* in_sizes, int n_in,
                              void* d_out, int out_size, void* d_ws, size_t ws_size,
                              hipStream_t stream) {
  const float* x          = (const float*)d_in[0];
  const int*   meas       = (const int*)d_in[1];
  const float* rank_embed = (const float*)d_in[2];
  const float* W1         = (const float*)d_in[3];
  const float* b1         = (const float*)d_in[4];
  const float* W2         = (const float*)d_in[5];
  const float* b2         = (const float*)d_in[6];
  float* out = (float*)d_out;

  int* qmeta = (int*)d_ws;                                       // 8 KB: counts/qtot/work
  int* lists = (int*)((char*)d_ws + 8192);                       // 768 KB
  short* W1T = (short*)((char*)d_ws + (800 << 10));              // 192 KB bf16
  float* rw  = (float*)((char*)d_ws + (1000 << 10));             // 15.4 KB f32

  hipMemsetAsync(d_ws, 0, 8192, stream);   // zero counts + queue region
  bucket_k<<<BS / 1024, 1024, 0, stream>>>(meas, qmeta, lists);
  prep_k<<<dim3(NEXP, 9), 256, 0, stream>>>(W1, rank_embed, b1, W1T, rw);
  build_q_k<<<1, 256, 0, stream>>>(qmeta, qmeta);
  moe_gemm_k<<<MAXQ, 256, 0, stream>>>(x, W1T, rw, W2, b2, qmeta, lists, out);
}

// Round 12
// 108.099 us; speedup vs baseline: 1.8011x; 1.0326x over previous
//
#include <hip/hip_runtime.h>
#include <hip/hip_bf16.h>

#define BS 32768
#define NWP 10
#define DD 256
#define NEXP 6
#define HH 64
#define OUT_DIM 2
#define MB 32
#define MAXQ 1032   // >= sum_e ceil(cnt_e/MB) worst case

typedef short bf16x8 __attribute__((ext_vector_type(8)));
typedef float f32x4 __attribute__((ext_vector_type(4)));
typedef __attribute__((address_space(3))) void as3void;
typedef const __attribute__((address_space(1))) void as1void;

__device__ inline short bfs(float f) {
  __hip_bfloat16 h = __float2bfloat16(f);   // RNE
  return __builtin_bit_cast(short, h);
}

// ------- kernel 1: bucket by expert (block-aggregated atomics, int lists) -------
__global__ __launch_bounds__(1024) void bucket_k(const int* __restrict__ cmd,
                                                 int* __restrict__ counts,
                                                 int* __restrict__ lists) {
  __shared__ int wcnt[16][NEXP];
  __shared__ int wbase[16][NEXP];
  const int tid = threadIdx.x;
  const int w = tid >> 6, lane = tid & 63;
  const int b = blockIdx.x * 1024 + tid;          // grid covers exactly BS
  const int e = cmd[b];
  #pragma unroll
  for (int ee = 0; ee < NEXP; ++ee) {
    unsigned long long m = __ballot(e == ee);
    if (lane == 0) wcnt[w][ee] = __popcll(m);
  }
  __syncthreads();
  if (tid < NEXP) {
    int tot = 0, pf[16];
    #pragma unroll
    for (int ww = 0; ww < 16; ++ww) { pf[ww] = tot; tot += wcnt[ww][tid]; }
    const int bb = atomicAdd(&counts[tid], tot);  // 6 atomics per block
    #pragma unroll
    for (int ww = 0; ww < 16; ++ww) wbase[ww][tid] = bb + pf[ww];
  }
  __syncthreads();
  #pragma unroll
  for (int ee = 0; ee < NEXP; ++ee) {
    unsigned long long m = __ballot(e == ee);     // same mask as pass 1
    if (e == ee) {
      const int nbelow = __popcll(m & ((1ull << lane) - 1ull));
      lists[ee * BS + wbase[w][ee] + nbelow] = b;
    }
  }
}

// ------- kernel 1b: prep, 54 blocks. parts 0-7: W1T slice; part 8: rw -------
__global__ void prep_k(const float* __restrict__ W1,
                       const float* __restrict__ re,
                       const float* __restrict__ b1,
                       short* __restrict__ W1T,
                       float* __restrict__ rw) {
  const int e = blockIdx.x;
  const int part = blockIdx.y;
  if (part < 8) {
    const int h = part * 8 + (threadIdx.x >> 5);
    const int d0 = (threadIdx.x & 31) * 8;
    const float* wp = W1 + (size_t)e * DD * HH + h;
    bf16x8 v;
    #pragma unroll
    for (int i = 0; i < 8; ++i) v[i] = bfs(wp[(size_t)(d0 + i) * HH]);
    *(bf16x8*)(W1T + ((size_t)e * HH + h) * DD + d0) = v;
  } else {
    for (int i = threadIdx.x; i < NWP * HH; i += 256) {
      const int n = i >> 6, h = i & 63;
      const float* rp = re + (size_t)n * DD;
      const float* wp = W1 + (size_t)e * DD * HH + h;
      float s = b1[e * HH + h];
      for (int d = 0; d < DD; ++d) s += rp[d] * wp[(size_t)d * HH];
      rw[((size_t)e * NWP + n) * HH + h] = s;     // fp32, exact
    }
  }
}

// two asm ds_read_b128 per k-step; compiler-invisible reads of the DMA'd tile
#define DSR(I, OFF) \
  asm volatile("ds_read_b128 %0, %1 offset:" OFF : "=v"(ra[I]) : "v"(a0)); \
  asm volatile("ds_read_b128 %0, %1 offset:" OFF : "=v"(rb[I]) : "v"(a1));

// ------- kernel 2: per-wave dbuf DMA pipeline, counted vmcnt, no in-loop barriers -------
__global__ __launch_bounds__(128, 1) void moe_gemm_k(
    const float* __restrict__ x,
    const short* __restrict__ W1T,     // [6][64][256] bf16, L2-resident
    const float* __restrict__ rwg,     // [6][10][64] f32 (b1 + re·W1)
    const float* __restrict__ W2,
    const float* __restrict__ b2,
    const int* __restrict__ qmeta,     // [0..5] = counts
    const int* __restrict__ lists,
    float* __restrict__ out)
{
  __shared__ float Xa[2][2][16 * DD];  // 64 KB: [wave][buf][16 rows fp32, src-swizzled]
  __shared__ float rwl[NWP][68];       // 2.72 KB rw[e]
  __shared__ float w2l[HH * OUT_DIM];  // 0.5 KB  W2[e]
  __shared__ float po[MB * NWP][2];    // 2.56 KB pre-cumsum outputs
  __shared__ int bidl[MB];             // item ids (LDS -> gb fetch is lgkm, not vmcnt)

  // decode (e, start) from blockIdx (no build_q kernel)
  const int wi = blockIdx.x;
  int acc0 = 0, e = -1, start = 0;
  #pragma unroll
  for (int ee = 0; ee < NEXP; ++ee) {
    const int nc = (qmeta[ee] + MB - 1) >> 5;
    if (e < 0 && wi < acc0 + nc) { e = ee; start = (wi - acc0) * MB; }
    acc0 += nc;
  }
  if (e < 0) return;
  const int cnt = qmeta[e];
  const int nb = min(MB, cnt - start);
  const int nrows = nb * NWP;

  const int tid = threadIdx.x;
  const int lane = tid & 63;
  const int wv = tid >> 6;             // 0 or 1
  const int arow = lane & 15;
  const int ag = lane >> 4;
  const int lbase = e * BS + start;

  // hoist all A-fragments: Wf[nt][ks] = W1T[h=nt*16+arow][ks*32+ag*8 .. +8)
  bf16x8 Wf[4][8];                     // 128 VGPR, static indices only
  {
    const short* wb = W1T + ((size_t)e * HH + arow) * DD + ag * 8;
    #pragma unroll
    for (int nt = 0; nt < 4; ++nt)
      #pragma unroll
      for (int ks = 0; ks < 8; ++ks)
        Wf[nt][ks] = *(const bf16x8*)(wb + (size_t)(nt * 16) * DD + ks * 32);
  }
  for (int i = tid; i < NWP * HH; i += 128)
    rwl[i >> 6][i & 63] = rwg[(size_t)e * NWP * HH + i];
  if (tid < HH * OUT_DIM) w2l[tid] = W2[(size_t)e * HH * OUT_DIM + tid];
  if (tid < nb) bidl[tid] = lists[lbase + tid];

  asm volatile("s_waitcnt vmcnt(0)" ::: "memory");  // Wf resident; clean vmcnt state
  __syncthreads();

  const int ntile = (nrows + 15) >> 4;

  // LDS byte base of this wave's buf0; read addrs carry the XOR involution
  const unsigned wb0 =
      (unsigned)(uintptr_t)(as3void*)&Xa[wv][0][0];
  const unsigned pk = (unsigned)((arow & 7) << 4);
  const unsigned roff = (unsigned)(arow * 1024) + (((unsigned)(ag * 32)) ^ pk);

  // issue one 16-row tile: 16 DMA, linear LDS dest, inverse-swizzled global src
  auto issue = [&](int t, int b) {
    #pragma unroll
    for (int r = 0; r < 16; ++r) {
      const int rowu = min(t * 16 + r, nrows - 1);   // uniform
      const int item = rowu / NWP;
      const int nn = rowu - item * NWP;
      const int gb = bidl[item];                     // LDS read: lgkm only
      const float* src = x + ((size_t)gb * NWP + nn) * DD
                       + ((((unsigned)lane * 16) ^ ((unsigned)(r & 7) << 4)) >> 2);
      __builtin_amdgcn_global_load_lds((as1void*)src,
                                       (as3void*)&Xa[wv][b][r * DD], 16, 0, 0);
    }
  };

  issue(wv, 0);
  int cur = 0;
  for (int t = wv; t < ntile; t += 2) {
    issue(t + 2, cur ^ 1);             // 16 DMA in flight across the whole compute
    asm volatile("s_waitcnt vmcnt(16)" ::: "memory");   // tile t's batch retired
    __builtin_amdgcn_sched_barrier(0);

    const unsigned a0 = wb0 + (cur ? 16384u : 0u) + roff;
    const unsigned a1 = a0 ^ 16u;
    f32x4 ra[8], rb[8];
    DSR(0, "0")   DSR(1, "128") DSR(2, "256") DSR(3, "384")
    DSR(4, "512") DSR(5, "640") DSR(6, "768") DSR(7, "896")
    asm volatile("s_waitcnt lgkmcnt(0)" ::: "memory");
    __builtin_amdgcn_sched_barrier(0);

    f32x4 acc[4] = {{0,0,0,0},{0,0,0,0},{0,0,0,0},{0,0,0,0}};
    #pragma unroll
    for (int ks = 0; ks < 8; ++ks) {
      bf16x8 bx;
      bx[0] = bfs(ra[ks][0]); bx[1] = bfs(ra[ks][1]);
      bx[2] = bfs(ra[ks][2]); bx[3] = bfs(ra[ks][3]);
      bx[4] = bfs(rb[ks][0]); bx[5] = bfs(rb[ks][1]);
      bx[6] = bfs(rb[ks][2]); bx[7] = bfs(rb[ks][3]);
      #pragma unroll
      for (int nt = 0; nt < 4; ++nt)
        acc[nt] = __builtin_amdgcn_mfma_f32_16x16x32_bf16(Wf[nt][ks], bx, acc[nt], 0, 0, 0);
    }

    // thin epilogue: lane owns batch-row t*16+arow; h = nt*16+ag*4+rg
    const int row = t * 16 + arow;
    const int rowc = min(row, nrows - 1);
    const int nn = rowc - (rowc / NWP) * NWP;
    float p0 = 0.f, p1 = 0.f;
    #pragma unroll
    for (int nt = 0; nt < 4; ++nt) {
      const int h0 = nt * 16 + ag * 4;
      const float4 rv = *(const float4*)&rwl[nn][h0];
      const float4 wa = *(const float4*)&w2l[h0 * 2];       // h0:{o0,o1} h1:{o0,o1}
      const float4 wb = *(const float4*)&w2l[h0 * 2 + 4];   // h2,h3
      const float h0v = fmaxf(acc[nt][0] + rv.x, 0.f);
      const float h1v = fmaxf(acc[nt][1] + rv.y, 0.f);
      const float h2v = fmaxf(acc[nt][2] + rv.z, 0.f);
      const float h3v = fmaxf(acc[nt][3] + rv.w, 0.f);
      p0 += h0v * wa.x + h1v * wa.z + h2v * wb.x + h3v * wb.z;
      p1 += h0v * wa.y + h1v * wa.w + h2v * wb.y + h3v * wb.w;
    }
    p0 += __shfl_xor(p0, 16); p1 += __shfl_xor(p1, 16);     // reduce over ag
    p0 += __shfl_xor(p0, 32); p1 += __shfl_xor(p1, 32);
    if (ag == 0 && row < nrows) {     // unique writer: tiles disjoint per wave
      po[row][0] = p0;
      po[row][1] = p1;
    }
    cur ^= 1;
  }

  __syncthreads();   // drains leftover DMA batch; po visible

  // fused cumsum + writeout: one thread per batch item
  if (tid < nb) {
    const int gb = bidl[tid];
    const float bb0 = b2[e * OUT_DIM + 0];
    const float bb1 = b2[e * OUT_DIM + 1];
    float v[NWP * OUT_DIM];
    float s0 = 0.f, s1 = 0.f;
    #pragma unroll
    for (int n = 0; n < NWP; ++n) {
      s0 += po[tid * NWP + n][0] + bb0;
      s1 += po[tid * NWP + n][1] + bb1;
      v[n * 2 + 0] = s0;
      v[n * 2 + 1] = s1;
    }
    float4* op = (float4*)(out + (size_t)gb * NWP * OUT_DIM);
    #pragma unroll
    for (int q = 0; q < 5; ++q)
      op[q] = make_float4(v[q * 4], v[q * 4 + 1], v[q * 4 + 2], v[q * 4 + 3]);
  }
}

extern "C" void kernel_launch(void* const* d_in, const int* in_sizes, int n_in,
                              void* d_out, int out_size, void* d_ws, size_t ws_size,
                              hipStream_t stream) {
  const float* x          = (const float*)d_in[0];
  const int*   meas       = (const int*)d_in[1];
  const float* rank_embed = (const float*)d_in[2];
  const float* W1         = (const float*)d_in[3];
  const float* b1         = (const float*)d_in[4];
  const float* W2         = (const float*)d_in[5];
  const float* b2         = (const float*)d_in[6];
  float* out = (float*)d_out;

  int* qmeta = (int*)d_ws;                                       // counts[6]
  int* lists = (int*)((char*)d_ws + 8192);                       // 768 KB
  short* W1T = (short*)((char*)d_ws + (800 << 10));              // 192 KB bf16
  float* rw  = (float*)((char*)d_ws + (1000 << 10));             // 15.4 KB f32

  hipMemsetAsync(d_ws, 0, 8192, stream);
  bucket_k<<<BS / 1024, 1024, 0, stream>>>(meas, qmeta, lists);
  prep_k<<<dim3(NEXP, 9), 256, 0, stream>>>(W1, rank_embed, b1, W1T, rw);
  moe_gemm_k<<<MAXQ, 128, 0, stream>>>(x, W1T, rw, W2, b2, qmeta, lists, out);
}

// Round 13
// 101.284 us; speedup vs baseline: 1.9223x; 1.0673x over previous
//
#include <hip/hip_runtime.h>
#include <hip/hip_bf16.h>

#define BS 32768
#define NWP 10
#define DD 256
#define NEXP 6
#define HH 64
#define OUT_DIM 2
#define MB 32
#define MAXQ 1032   // >= sum_e ceil(cnt_e/MB) worst case

typedef short bf16x8 __attribute__((ext_vector_type(8)));
typedef float f32x4 __attribute__((ext_vector_type(4)));

__device__ inline short bfs(float f) {
  __hip_bfloat16 h = __float2bfloat16(f);   // RNE
  return __builtin_bit_cast(short, h);
}

// ------- kernel 1 (fused aux): blocks 0-31 bucket; 32-43 W1T; 44-49 rw -------
__global__ __launch_bounds__(1024) void aux_k(const int* __restrict__ cmd,
                                              const float* __restrict__ W1,
                                              const float* __restrict__ re,
                                              const float* __restrict__ b1,
                                              int* __restrict__ counts,
                                              int* __restrict__ lists,
                                              short* __restrict__ W1T,
                                              float* __restrict__ rw) {
  const int bid = blockIdx.x;
  const int tid = threadIdx.x;

  if (bid < 32) {               // ---- bucket by expert (block-aggregated atomics)
    __shared__ int wcnt[16][NEXP];
    __shared__ int wbase[16][NEXP];
    const int w = tid >> 6, lane = tid & 63;
    const int b = bid * 1024 + tid;               // grid covers exactly BS
    const int e = cmd[b];
    #pragma unroll
    for (int ee = 0; ee < NEXP; ++ee) {
      unsigned long long m = __ballot(e == ee);
      if (lane == 0) wcnt[w][ee] = __popcll(m);
    }
    __syncthreads();
    if (tid < NEXP) {
      int tot = 0, pf[16];
      #pragma unroll
      for (int ww = 0; ww < 16; ++ww) { pf[ww] = tot; tot += wcnt[ww][tid]; }
      const int bb = atomicAdd(&counts[tid], tot);
      #pragma unroll
      for (int ww = 0; ww < 16; ++ww) wbase[ww][tid] = bb + pf[ww];
    }
    __syncthreads();
    #pragma unroll
    for (int ee = 0; ee < NEXP; ++ee) {
      unsigned long long m = __ballot(e == ee);   // same mask as pass 1
      if (e == ee) {
        const int nbelow = __popcll(m & ((1ull << lane) - 1ull));
        lists[ee * BS + wbase[w][ee] + nbelow] = b;
      }
    }
  } else if (bid < 44) {        // ---- W1 -> W1T bf16 [e][h][d]
    const int e = (bid - 32) >> 1;
    const int h = ((bid - 32) & 1) * 32 + (tid >> 5);
    const int d0 = (tid & 31) * 8;
    const float* wp = W1 + (size_t)e * DD * HH + h;
    bf16x8 v;
    #pragma unroll
    for (int i = 0; i < 8; ++i) v[i] = bfs(wp[(size_t)(d0 + i) * HH]);
    *(bf16x8*)(W1T + ((size_t)e * HH + h) * DD + d0) = v;
  } else {                      // ---- rw[e][n][h] = b1 + re·W1 (fp32 exact)
    const int e = bid - 44;
    if (tid < NWP * HH) {
      const int n = tid >> 6, h = tid & 63;
      const float* rp = re + (size_t)n * DD;
      const float* wp = W1 + (size_t)e * DD * HH + h;
      float s = b1[e * HH + h];
      for (int d = 0; d < DD; ++d) s += rp[d] * wp[(size_t)d * HH];
      rw[((size_t)e * NWP + n) * HH + h] = s;
    }
  }
}

// ------- kernel 2: R11 body; inline queue decode; NON-TEMPORAL x loads -------
__global__ __launch_bounds__(256, 2) void moe_gemm_k(
    const float* __restrict__ x,
    const short* __restrict__ W1T,     // [6][64][256] bf16, L2-resident
    const float* __restrict__ rwg,     // [6][10][64] f32 (b1 + re·W1)
    const float* __restrict__ W2,
    const float* __restrict__ b2,
    const int* __restrict__ qmeta,     // [0..5] counts
    const int* __restrict__ lists,
    float* __restrict__ out)
{
  __shared__ short Xa[4][16 * DD];     // 32 KB per-wave single-buffer tiles
  __shared__ float rwl[NWP][68];       // 2.72 KB rw[e]
  __shared__ float w2l[HH * OUT_DIM];  // 0.5 KB  W2[e]
  __shared__ float po[MB * NWP][2];    // 2.56 KB pre-cumsum outputs

  // decode (e, start) from blockIdx (no build_q kernel)
  const int wi = blockIdx.x;
  int acc0 = 0, e = -1, start = 0;
  #pragma unroll
  for (int ee = 0; ee < NEXP; ++ee) {
    const int nc = (qmeta[ee] + MB - 1) >> 5;
    if (e < 0 && wi < acc0 + nc) { e = ee; start = (wi - acc0) * MB; }
    acc0 += nc;
  }
  if (e < 0) return;
  const int cnt = qmeta[e];
  const int nb = min(MB, cnt - start);
  const int nrows = nb * NWP;

  const int tid = threadIdx.x;
  const int lane = tid & 63;
  const int wv = tid >> 6;
  const int arow = lane & 15;
  const int ag = lane >> 4;
  const int lbase = e * BS + start;

  // hoist all A-fragments: Wf[nt][ks] = W1T[h=nt*16+arow][ks*32+ag*8 .. +8)
  bf16x8 Wf[4][8];                     // 128 VGPR, static indices only
  {
    const short* wb = W1T + ((size_t)e * HH + arow) * DD + ag * 8;
    #pragma unroll
    for (int nt = 0; nt < 4; ++nt)
      #pragma unroll
      for (int ks = 0; ks < 8; ++ks)
        Wf[nt][ks] = *(const bf16x8*)(wb + (size_t)(nt * 16) * DD + ks * 32);
  }
  for (int i = tid; i < NWP * HH; i += 256)
    rwl[i >> 6][i & 63] = rwg[(size_t)e * NWP * HH + i];
  if (tid < HH * OUT_DIM) w2l[tid] = W2[(size_t)e * HH * OUT_DIM + tid];

  __syncthreads();   // tables ready; no barriers until cumsum

  short* Xw = &Xa[wv][0];
  const int ntile = (nrows + 15) >> 4;

  for (int t = wv; t < ntile; t += 4) {          // tiles disjoint per wave
    // stage 16 rows: coalesced 1KB/instr NON-TEMPORAL loads (x has zero reuse
    // within a pass; retention only feeds L3 thrash which caps the stream)
    #pragma unroll
    for (int r = 0; r < 16; ++r) {
      const int rowu = __builtin_amdgcn_readfirstlane(min(t * 16 + r, nrows - 1));
      const int item = rowu / NWP;
      const int nn = rowu - item * NWP;
      const int gb = lists[lbase + item];        // uniform address -> scalar load
      const f32x4 xv = __builtin_nontemporal_load(
          (const f32x4*)(x + ((size_t)gb * NWP + nn) * DD + lane * 4));
      short4 pk = make_short4(bfs(xv[0]), bfs(xv[1]), bfs(xv[2]), bfs(xv[3]));
      *(short4*)&Xw[r * DD + ((lane * 4) ^ ((r & 7) << 3))] = pk;
    }

    // compute: S^T = W1^T · x ; only 8 ds_reads per tile
    f32x4 acc[4] = {{0,0,0,0},{0,0,0,0},{0,0,0,0},{0,0,0,0}};
    #pragma unroll
    for (int ks = 0; ks < 8; ++ks) {
      const int kidx = ks * 32 + ag * 8;
      const bf16x8 bx = *(const bf16x8*)&Xw[arow * DD + (kidx ^ ((arow & 7) << 3))];
      #pragma unroll
      for (int nt = 0; nt < 4; ++nt)
        acc[nt] = __builtin_amdgcn_mfma_f32_16x16x32_bf16(Wf[nt][ks], bx, acc[nt], 0, 0, 0);
    }

    // thin epilogue: lane owns batch-row t*16+arow; h = nt*16+ag*4+rg
    const int row = t * 16 + arow;
    const int rowc = min(row, nrows - 1);
    const int nn = rowc - (rowc / NWP) * NWP;
    float p0 = 0.f, p1 = 0.f;
    #pragma unroll
    for (int nt = 0; nt < 4; ++nt) {
      const int h0 = nt * 16 + ag * 4;
      const float4 rv = *(const float4*)&rwl[nn][h0];
      const float4 wa = *(const float4*)&w2l[h0 * 2];       // h0:{o0,o1} h1:{o0,o1}
      const float4 wb = *(const float4*)&w2l[h0 * 2 + 4];   // h2,h3
      const float h0v = fmaxf(acc[nt][0] + rv.x, 0.f);
      const float h1v = fmaxf(acc[nt][1] + rv.y, 0.f);
      const float h2v = fmaxf(acc[nt][2] + rv.z, 0.f);
      const float h3v = fmaxf(acc[nt][3] + rv.w, 0.f);
      p0 += h0v * wa.x + h1v * wa.z + h2v * wb.x + h3v * wb.z;
      p1 += h0v * wa.y + h1v * wa.w + h2v * wb.y + h3v * wb.w;
    }
    p0 += __shfl_xor(p0, 16); p1 += __shfl_xor(p1, 16);     // reduce over ag
    p0 += __shfl_xor(p0, 32); p1 += __shfl_xor(p1, 32);
    if (ag == 0 && row < nrows) {     // unique writer: tiles disjoint per wave
      po[row][0] = p0;
      po[row][1] = p1;
    }
  }

  __syncthreads();   // all po stores visible

  // fused cumsum + writeout: one thread per batch item
  if (tid < nb) {
    const int gb = lists[lbase + tid];
    const float bb0 = b2[e * OUT_DIM + 0];
    const float bb1 = b2[e * OUT_DIM + 1];
    float v[NWP * OUT_DIM];
    float s0 = 0.f, s1 = 0.f;
    #pragma unroll
    for (int n = 0; n < NWP; ++n) {
      s0 += po[tid * NWP + n][0] + bb0;
      s1 += po[tid * NWP + n][1] + bb1;
      v[n * 2 + 0] = s0;
      v[n * 2 + 1] = s1;
    }
    float4* op = (float4*)(out + (size_t)gb * NWP * OUT_DIM);
    #pragma unroll
    for (int q = 0; q < 5; ++q)
      op[q] = make_float4(v[q * 4], v[q * 4 + 1], v[q * 4 + 2], v[q * 4 + 3]);
  }
}

extern "C" void kernel_launch(void* const* d_in, const int* in_sizes, int n_in,
                              void* d_out, int out_size, void* d_ws, size_t ws_size,
                              hipStream_t stream) {
  const float* x          = (const float*)d_in[0];
  const int*   meas       = (const int*)d_in[1];
  const float* rank_embed = (const float*)d_in[2];
  const float* W1         = (const float*)d_in[3];
  const float* b1         = (const float*)d_in[4];
  const float* W2         = (const float*)d_in[5];
  const float* b2         = (const float*)d_in[6];
  float* out = (float*)d_out;

  int* qmeta = (int*)d_ws;                                       // counts[6]
  int* lists = (int*)((char*)d_ws + 8192);                       // 768 KB
  short* W1T = (short*)((char*)d_ws + (800 << 10));              // 192 KB bf16
  float* rw  = (float*)((char*)d_ws + (1000 << 10));             // 15.4 KB f32

  hipMemsetAsync(d_ws, 0, 256, stream);   // zero counts
  aux_k<<<50, 1024, 0, stream>>>(meas, W1, rank_embed, b1, qmeta, lists, W1T, rw);
  moe_gemm_k<<<MAXQ, 256, 0, stream>>>(x, W1T, rw, W2, b2, qmeta, lists, out);
}